// Round 1
// baseline (4188.726 us; speedup 1.0000x reference)
//
#include <hip/hip_runtime.h>
#include <hip/hip_bf16.h>

// Problem constants (fixed by the reference)
#define B_  64
#define T_  128
#define E_  300
#define H_  512
#define G4  2048   // 4*H
#define R_  128    // 2*B (s1 and s2 batched; they share LSTM weights)
#define C_  256
#define M_  512
#define V_  32000

#define BK 16

__device__ __forceinline__ float fsig(float x) { return 1.0f / (1.0f + __expf(-x)); }
__device__ __forceinline__ float ftanh(float x) {
    // guarded fast tanh: exp overflow-safe, ~1e-6 abs error
    float a = fminf(fabsf(x), 15.0f);
    float e = __expf(2.0f * a);
    float r = (e - 1.0f) / (e + 1.0f);
    return copysignf(r, x);
}
__device__ __forceinline__ unsigned short f2bf(float f) {
    __hip_bfloat16 h = __float2bfloat16(f);
    return *reinterpret_cast<unsigned short*>(&h);
}

// ---------------------------------------------------------------------------
// K1: embedding gather + input GEMM.  xW[dir][r][t][g] = emb[tok] @ Wih^T + b
// dir 0: natural time order; dir 1: tokens reversed within valid length.
// Output stored bf16 (rounded after fp32 accumulate).
// Tiles with t0 >= len[r] are dead (never consumed) -> early exit.
// ---------------------------------------------------------------------------
__global__ __launch_bounds__(256) void k_embed_gemm(
    const int* __restrict__ s1, const int* __restrict__ s2,
    const int* __restrict__ l1, const int* __restrict__ l2,
    const float* __restrict__ emb,
    const float* __restrict__ Wih_f, const float* __restrict__ b_f,
    const float* __restrict__ Wih_b, const float* __restrict__ b_b,
    __hip_bfloat16* __restrict__ xf, __hip_bfloat16* __restrict__ xb)
{
    const int dir = blockIdx.z;
    const int m0  = blockIdx.y * 64;   // (r,t) row-tile: r fixed, t in [t0, t0+64)
    const int n0  = blockIdx.x * 64;
    const int r   = m0 >> 7;
    const int t0  = m0 & 127;
    const int L   = (r < B_) ? l1[r] : l2[r - B_];
    if (L <= t0) return;               // fully-dead tile: outputs never read

    const int tid = threadIdx.x;
    const int tx = tid & 15, ty = tid >> 4;

    __shared__ int toks[64];
    __shared__ __align__(16) float As[BK][64 + 8];
    __shared__ __align__(16) float Bs[BK][64 + 8];

    if (tid < 64) {
        int t  = t0 + tid;
        int tt = (dir == 0) ? t : ((t < L) ? (L - 1 - t) : t);
        toks[tid] = (r < B_) ? s1[r * T_ + tt] : s2[(r - B_) * T_ + tt];
    }
    __syncthreads();

    const float* Wih  = dir ? Wih_b : Wih_f;
    const float* bias = dir ? b_b : b_f;

    float acc[4][4] = {};

    for (int k0 = 0; k0 < E_; k0 += BK) {
#pragma unroll
        for (int p = 0; p < 4; ++p) {      // A: 64 rows x 16 k (gather from emb)
            int l = tid + p * 256;
            int kk = l & 15, mi = l >> 4;
            int k = k0 + kk;
            As[kk][mi] = (k < E_) ? emb[(size_t)toks[mi] * E_ + k] : 0.0f;
        }
#pragma unroll
        for (int p = 0; p < 4; ++p) {      // B: 64 cols x 16 k
            int l = tid + p * 256;
            int kk = l & 15, ni = l >> 4;
            int k = k0 + kk;
            Bs[kk][ni] = (k < E_) ? Wih[(size_t)(n0 + ni) * E_ + k] : 0.0f;
        }
        __syncthreads();
#pragma unroll
        for (int kk = 0; kk < BK; ++kk) {
            float4 av = *(const float4*)&As[kk][ty * 4];
            float4 bv = *(const float4*)&Bs[kk][tx * 4];
            float a[4] = {av.x, av.y, av.z, av.w};
            float b[4] = {bv.x, bv.y, bv.z, bv.w};
#pragma unroll
            for (int i = 0; i < 4; ++i)
#pragma unroll
                for (int j = 0; j < 4; ++j)
                    acc[i][j] += a[i] * b[j];
        }
        __syncthreads();
    }

    __hip_bfloat16* xout = dir ? xb : xf;
    const int nbase = n0 + tx * 4;
#pragma unroll
    for (int i = 0; i < 4; ++i) {
        int m = m0 + ty * 4 + i;
        ushort4 pk;
        pk.x = f2bf(acc[i][0] + bias[nbase + 0]);
        pk.y = f2bf(acc[i][1] + bias[nbase + 1]);
        pk.z = f2bf(acc[i][2] + bias[nbase + 2]);
        pk.w = f2bf(acc[i][3] + bias[nbase + 3]);
        *(ushort4*)&xout[(size_t)m * G4 + nbase] = pk;
    }
}

// ---------------------------------------------------------------------------
// K2: one LSTM time step, both streams (fwd/bwd), batch 128.
// Block = (stream, 32-row block, 16-position block). Each thread ends up
// holding all 4 gates (i,f,g,o) of 2 (row,pos) cells -> fused gate epilogue,
// no cross-thread exchange. h written to hf/hb[r][t][:] (doubles as the
// h-state for step t+1; inter-dispatch barrier provides visibility/fences).
// ---------------------------------------------------------------------------
__global__ __launch_bounds__(256) void k_lstm_step(
    int t,
    const __hip_bfloat16* __restrict__ xf, const __hip_bfloat16* __restrict__ xb,
    float* __restrict__ hf, float* __restrict__ hb,
    float* __restrict__ cF, float* __restrict__ cB,
    const float* __restrict__ Whh_f, const float* __restrict__ Whh_b,
    const float* __restrict__ s1_h0, const float* __restrict__ s1_c0,
    const float* __restrict__ s2_h0, const float* __restrict__ s2_c0)
{
    const int bx = blockIdx.x;
    const int s  = bx >> 7;          // 0 = fwd, 1 = bwd
    const int rb = (bx >> 5) & 3;    // 4 row-blocks of 32
    const int pb = bx & 31;          // 32 position-blocks of 16
    const int r0 = rb * 32;
    const int j0 = pb * 16;

    const __hip_bfloat16* xW = s ? xb : xf;
    const float* Whh = s ? Whh_b : Whh_f;
    float* hOut = s ? hb : hf;
    float* cWs  = s ? cB : cF;

    const int tid = threadIdx.x;
    const int tx = tid & 15, ty = tid >> 4;

    __shared__ __align__(16) float Hs[16][32 + 4];
    __shared__ __align__(16) float Ws[16][64 + 8];

    float acc[2][4] = {};

    for (int k0 = 0; k0 < H_; k0 += 16) {
#pragma unroll
        for (int p = 0; p < 2; ++p) {   // h_prev: 32 rows x 16 k
            int l = tid + p * 256;
            int kk = l & 15, rr = l >> 4;
            int rg = r0 + rr;
            float hv;
            if (t == 0) {
                const float* h0 = (rg < B_) ? s1_h0 : s2_h0;
                int rl = (rg < B_) ? rg : rg - B_;
                hv = h0[(size_t)s * B_ * H_ + (size_t)rl * H_ + k0 + kk];
            } else {
                hv = hOut[((size_t)rg * T_ + (t - 1)) * H_ + k0 + kk];
            }
            Hs[kk][rr] = hv;
        }
#pragma unroll
        for (int p = 0; p < 4; ++p) {   // Whh slice: 64 gcols x 16 k, ci = jj*4+gate
            int l = tid + p * 256;
            int kk = l & 15, ci = l >> 4;
            int gate = ci & 3, jj = ci >> 2;
            Ws[kk][ci] = Whh[(size_t)(gate * H_ + j0 + jj) * H_ + k0 + kk];
        }
        __syncthreads();
#pragma unroll
        for (int kk = 0; kk < 16; ++kk) {
            float2 av = *(const float2*)&Hs[kk][ty * 2];
            float4 bv = *(const float4*)&Ws[kk][tx * 4];
            float a[2] = {av.x, av.y};
            float b[4] = {bv.x, bv.y, bv.z, bv.w};
#pragma unroll
            for (int i = 0; i < 2; ++i)
#pragma unroll
                for (int j = 0; j < 4; ++j)
                    acc[i][j] += a[i] * b[j];
        }
        __syncthreads();
    }

    // gate epilogue: thread holds (i,f,g,o) for rows r0+ty*2+{0,1}, pos j0+tx
    const int jpos = j0 + tx;
#pragma unroll
    for (int i = 0; i < 2; ++i) {
        int r = r0 + ty * 2 + i;
        size_t xbase = ((size_t)r * T_ + t) * G4;
        float gi = acc[i][0] + __bfloat162float(xW[xbase + 0 * H_ + jpos]);
        float gf = acc[i][1] + __bfloat162float(xW[xbase + 1 * H_ + jpos]);
        float gg = acc[i][2] + __bfloat162float(xW[xbase + 2 * H_ + jpos]);
        float go = acc[i][3] + __bfloat162float(xW[xbase + 3 * H_ + jpos]);
        size_t cidx = (size_t)r * H_ + jpos;
        float c_old;
        if (t == 0) {
            const float* c0 = (r < B_) ? s1_c0 : s2_c0;
            int rl = (r < B_) ? r : r - B_;
            c_old = c0[(size_t)s * B_ * H_ + (size_t)rl * H_ + jpos];
        } else {
            c_old = cWs[cidx];
        }
        float cn = fsig(gf) * c_old + fsig(gi) * ftanh(gg);
        float hn = fsig(go) * ftanh(cn);
        cWs[cidx] = cn;
        hOut[((size_t)r * T_ + t) * H_ + jpos] = hn;
    }
}

// ---------------------------------------------------------------------------
// K3a: U[r,t,c] = tanh( Hout[r,t,:] @ S1W[c,:] ), Hout = [hf(t) ; hb(len-1-t)]
// Same tile skeleton as K1; dead row-tiles skipped.
// ---------------------------------------------------------------------------
__global__ __launch_bounds__(256) void k_attn_gemm(
    const float* __restrict__ hf, const float* __restrict__ hb,
    const int* __restrict__ l1, const int* __restrict__ l2,
    const float* __restrict__ S1W, float* __restrict__ U)
{
    const int m0 = blockIdx.y * 64;
    const int n0 = blockIdx.x * 64;
    const int r  = m0 >> 7;
    const int t0 = m0 & 127;
    const int L  = (r < B_) ? l1[r] : l2[r - B_];
    if (L <= t0) return;

    const int tid = threadIdx.x;
    const int tx = tid & 15, ty = tid >> 4;

    __shared__ __align__(16) float As[BK][64 + 8];
    __shared__ __align__(16) float Bs[BK][64 + 8];

    float acc[4][4] = {};

    for (int k0 = 0; k0 < 2 * H_; k0 += BK) {
#pragma unroll
        for (int p = 0; p < 4; ++p) {
            int l = tid + p * 256;
            int kk = l & 15, mi = l >> 4;
            int tpos = t0 + mi;
            int k = k0 + kk;
            float v;
            if (k < H_) {
                v = hf[((size_t)r * T_ + tpos) * H_ + k];
            } else {
                int tt = (tpos < L) ? (L - 1 - tpos) : tpos;  // stay in-bounds for dead rows
                v = hb[((size_t)r * T_ + tt) * H_ + (k - H_)];
            }
            As[kk][mi] = v;
        }
#pragma unroll
        for (int p = 0; p < 4; ++p) {
            int l = tid + p * 256;
            int kk = l & 15, ni = l >> 4;
            Bs[kk][ni] = S1W[(size_t)(n0 + ni) * (2 * H_) + k0 + kk];
        }
        __syncthreads();
#pragma unroll
        for (int kk = 0; kk < BK; ++kk) {
            float4 av = *(const float4*)&As[kk][ty * 4];
            float4 bv = *(const float4*)&Bs[kk][tx * 4];
            float a[4] = {av.x, av.y, av.z, av.w};
            float b[4] = {bv.x, bv.y, bv.z, bv.w};
#pragma unroll
            for (int i = 0; i < 4; ++i)
#pragma unroll
                for (int j = 0; j < 4; ++j)
                    acc[i][j] += a[i] * b[j];
        }
        __syncthreads();
    }
#pragma unroll
    for (int i = 0; i < 4; ++i) {
        int m = m0 + ty * 4 + i;
#pragma unroll
        for (int j = 0; j < 4; ++j)
            U[(size_t)m * C_ + n0 + tx * 4 + j] = ftanh(acc[i][j]);
    }
}

// ---------------------------------------------------------------------------
// K3b: per row r: scores = U@S2W over valid t, masked softmax, pooled = attn@Hout
// ---------------------------------------------------------------------------
__global__ __launch_bounds__(256) void k_attn_pool(
    const float* __restrict__ hf, const float* __restrict__ hb,
    const float* __restrict__ U, const float* __restrict__ S2W,
    const int* __restrict__ l1, const int* __restrict__ l2,
    float* __restrict__ pooled)
{
    const int r = blockIdx.x;
    const int L = (r < B_) ? l1[r] : l2[r - B_];
    const int tid = threadIdx.x;

    __shared__ float att[T_];

    if (tid < T_) {
        float sc = 0.0f;
        if (tid < L) {
            const float* u = &U[(size_t)(r * T_ + tid) * C_];
            for (int c = 0; c < C_; ++c) sc += u[c] * S2W[c];
        }
        att[tid] = sc;
    }
    __syncthreads();

    float mx = -1e30f;
    for (int tt = 0; tt < L; ++tt) mx = fmaxf(mx, att[tt]);
    __syncthreads();
    if (tid < T_) att[tid] = (tid < L) ? __expf(att[tid] - mx) : 0.0f;
    __syncthreads();
    float sum = 0.0f;
    for (int tt = 0; tt < L; ++tt) sum += att[tt];
    float inv = 1.0f / sum;

    for (int d = tid; d < 2 * H_; d += 256) {
        float a = 0.0f;
        for (int tt = 0; tt < L; ++tt) {
            float hv = (d < H_) ? hf[((size_t)r * T_ + tt) * H_ + d]
                                : hb[((size_t)r * T_ + (L - 1 - tt)) * H_ + (d - H_)];
            a += att[tt] * hv;
        }
        pooled[(size_t)r * (2 * H_) + d] = a * inv;
    }
}

// ---------------------------------------------------------------------------
// K4: merged = [r1+r2, (r1-r2)^2]; out = sigmoid((merged@mlpW^T+mlpb)@outW^T+outb)
// One block per batch element b; final dot fused via LDS reduction (CLS=1).
// ---------------------------------------------------------------------------
__global__ __launch_bounds__(256) void k_mlp_out(
    const float* __restrict__ pooled,
    const float* __restrict__ mlpW, const float* __restrict__ mlpb,
    const float* __restrict__ outW, const float* __restrict__ outb,
    float* __restrict__ out)
{
    const int b = blockIdx.x;
    const int tid = threadIdx.x;
    __shared__ float sm[2 * G4 / 2];   // 2048
    __shared__ float om[M_];
    __shared__ float red[256];

    for (int d = tid; d < 2048; d += 256) {
        float v;
        if (d < 1024) {
            v = pooled[(size_t)b * 1024 + d] + pooled[(size_t)(B_ + b) * 1024 + d];
        } else {
            int dd = d - 1024;
            float w = pooled[(size_t)b * 1024 + dd] - pooled[(size_t)(B_ + b) * 1024 + dd];
            v = w * w;
        }
        sm[d] = v;
    }
    __syncthreads();

    for (int mm = tid; mm < M_; mm += 256) {
        float a = mlpb[mm];
        const float* wrow = &mlpW[(size_t)mm * 2048];
        for (int k = 0; k < 2048; ++k) a += sm[k] * wrow[k];
        om[mm] = a;
    }
    __syncthreads();

    float p = om[tid] * outW[tid] + om[tid + 256] * outW[tid + 256];
    red[tid] = p;
    __syncthreads();
    for (int off = 128; off > 0; off >>= 1) {
        if (tid < off) red[tid] += red[tid + off];
        __syncthreads();
    }
    if (tid == 0) out[b] = 1.0f / (1.0f + __expf(-(red[0] + outb[0])));
}

// ---------------------------------------------------------------------------
extern "C" void kernel_launch(void* const* d_in, const int* in_sizes, int n_in,
                              void* d_out, int out_size, void* d_ws, size_t ws_size,
                              hipStream_t stream)
{
    const int*   s1    = (const int*)d_in[0];
    const int*   s2    = (const int*)d_in[1];
    const int*   l1    = (const int*)d_in[2];
    const int*   l2    = (const int*)d_in[3];
    const float* s1_h0 = (const float*)d_in[4];
    const float* s1_c0 = (const float*)d_in[5];
    const float* s2_h0 = (const float*)d_in[6];
    const float* s2_c0 = (const float*)d_in[7];
    const float* emb   = (const float*)d_in[8];
    const float* Wih_f = (const float*)d_in[9];
    const float* Whh_f = (const float*)d_in[10];
    const float* b_f   = (const float*)d_in[11];
    const float* Wih_b = (const float*)d_in[12];
    const float* Whh_b = (const float*)d_in[13];
    const float* b_b   = (const float*)d_in[14];
    const float* S1W   = (const float*)d_in[15];
    const float* S2W   = (const float*)d_in[16];
    const float* mlpW  = (const float*)d_in[17];
    const float* mlpb  = (const float*)d_in[18];
    const float* outW  = (const float*)d_in[19];
    const float* outb  = (const float*)d_in[20];
    float* out = (float*)d_out;

    // Workspace layout (~210 MB total):
    //   xf,xb : [R,T,4H] bf16   (input-GEMM results, bf16-rounded)
    //   hf,hb : [R,T,H]  f32    (all LSTM hidden states; hb in reversed time)
    //   cF,cB : [R,H]    f32    (cell state, in-place per step)
    //   U     : [R*T,C]  f32    (tanh(S1 @ Hout))
    //   pooled: [R,2H]   f32
    __hip_bfloat16* xf = (__hip_bfloat16*)d_ws;
    __hip_bfloat16* xb = xf + (size_t)R_ * T_ * G4;
    float* hf = (float*)(xb + (size_t)R_ * T_ * G4);
    float* hb = hf + (size_t)R_ * T_ * H_;
    float* cF = hb + (size_t)R_ * T_ * H_;
    float* cB = cF + (size_t)R_ * H_;
    float* U  = cB + (size_t)R_ * H_;
    float* pooled = U + (size_t)R_ * T_ * C_;

    dim3 g1(32, 256, 2);
    k_embed_gemm<<<g1, 256, 0, stream>>>(s1, s2, l1, l2, emb,
                                         Wih_f, b_f, Wih_b, b_b, xf, xb);

    for (int t = 0; t < T_; ++t)
        k_lstm_step<<<256, 256, 0, stream>>>(t, xf, xb, hf, hb, cF, cB,
                                             Whh_f, Whh_b,
                                             s1_h0, s1_c0, s2_h0, s2_c0);

    k_attn_gemm<<<dim3(4, 256), 256, 0, stream>>>(hf, hb, l1, l2, S1W, U);
    k_attn_pool<<<128, 256, 0, stream>>>(hf, hb, U, S2W, l1, l2, pooled);
    k_mlp_out<<<64, 256, 0, stream>>>(pooled, mlpW, mlpb, outW, outb, out);
}

// Round 2
// 2210.850 us; speedup vs baseline: 1.8946x; 1.8946x over previous
//
#include <hip/hip_runtime.h>
#include <hip/hip_bf16.h>

// Problem constants (fixed by the reference)
#define B_  64
#define T_  128
#define E_  300
#define EP  320     // E padded to multiple of 32 for MFMA K-loop
#define H_  512
#define G4  2048    // 4*H
#define R_  128     // 2*B (s1+s2 batched; shared LSTM weights)
#define C_  256
#define M_  512
#define TS  (T_ + 1)  // h time slots: slot 0 = h0, slot t+1 = h(t)

typedef short bf16x8 __attribute__((ext_vector_type(8)));
typedef float f32x4  __attribute__((ext_vector_type(4)));
#define MFMA(a, b, c) __builtin_amdgcn_mfma_f32_16x16x32_bf16((a), (b), (c), 0, 0, 0)

__device__ __forceinline__ float fsig(float x) { return 1.0f / (1.0f + __expf(-x)); }
__device__ __forceinline__ float ftanh(float x) {
    float a = fminf(fabsf(x), 15.0f);
    float e = __expf(2.0f * a);
    return copysignf((e - 1.0f) / (e + 1.0f), x);
}
__device__ __forceinline__ ushort f2bf(float f) {
    __hip_bfloat16 h = __float2bfloat16(f);
    return *reinterpret_cast<ushort*>(&h);
}
__device__ __forceinline__ float bf2f(ushort u) {
    __hip_bfloat16 h = *reinterpret_cast<__hip_bfloat16*>(&u);
    return __bfloat162float(h);
}

// ---------------------------------------------------------------------------
// P0: f32 -> bf16 row-wise convert with K padding (zeros in [sk, dk)).
// ---------------------------------------------------------------------------
__global__ __launch_bounds__(256) void k_cvt(const float* __restrict__ src,
                                             ushort* __restrict__ dst,
                                             int sk, int dk)
{
    const int r = blockIdx.x;
    for (int c = threadIdx.x; c < dk; c += 256)
        dst[(long)r * dk + c] = (c < sk) ? f2bf(src[(long)r * sk + c]) : (ushort)0;
}

// P1: init h slot 0 (bf16) and c (f32) from the h0/c0 inputs.
__global__ __launch_bounds__(256) void k_init(
    const float* __restrict__ s1_h0, const float* __restrict__ s1_c0,
    const float* __restrict__ s2_h0, const float* __restrict__ s2_c0,
    ushort* __restrict__ hfB, ushort* __restrict__ hbB,
    float* __restrict__ cF, float* __restrict__ cB)
{
    const int r = blockIdx.x;                    // 0..127
    const int rl = (r < B_) ? r : r - B_;
    const float* h0 = (r < B_) ? s1_h0 : s2_h0;  // [2][B][H]
    const float* c0 = (r < B_) ? s1_c0 : s2_c0;
    for (int j = threadIdx.x; j < H_; j += 256) {
        hfB[(long)r * TS * H_ + j] = f2bf(h0[(long)0 * B_ * H_ + (long)rl * H_ + j]);
        hbB[(long)r * TS * H_ + j] = f2bf(h0[(long)1 * B_ * H_ + (long)rl * H_ + j]);
        cF[r * H_ + j] = c0[(long)0 * B_ * H_ + (long)rl * H_ + j];
        cB[r * H_ + j] = c0[(long)1 * B_ * H_ + (long)rl * H_ + j];
    }
}

// ---------------------------------------------------------------------------
// K1: embedding gather + input GEMM via bf16 MFMA.
// xW[dir][r][t][gatecol] = bf16( emb[tok] @ Wih^T + b ).  Tile 64(m) x 128(n),
// m = r*T + t with tile spanning one r, t half -> dead-tile skip on t0 >= len.
// 4 waves arranged 2x2, each 32x64 (2 m-tiles x 4 n-tiles of 16x16x32).
// ---------------------------------------------------------------------------
__global__ __launch_bounds__(256) void k_embed_mfma(
    const int* __restrict__ s1, const int* __restrict__ s2,
    const int* __restrict__ l1, const int* __restrict__ l2,
    const ushort* __restrict__ embB,
    const ushort* __restrict__ WihBf, const ushort* __restrict__ WihBb,
    const float* __restrict__ b_f, const float* __restrict__ b_b,
    ushort* __restrict__ xf, ushort* __restrict__ xb)
{
    const int dir = blockIdx.z;
    const int r   = blockIdx.y >> 1;
    const int t0  = (blockIdx.y & 1) * 64;
    const int N0  = blockIdx.x * 128;
    const int L   = (r < B_) ? l1[r] : l2[r - B_];
    if (L <= t0) return;

    const int tid = threadIdx.x;
    const int lane = tid & 63, w = tid >> 6;
    const int wm = w & 1, wn = w >> 1;
    const int l15 = lane & 15, q8 = (lane >> 4) * 8;

    __shared__ int toks[64];
    __shared__ __align__(16) ushort As[64][40];   // stride 40 -> 2-way banks (free)
    __shared__ __align__(16) ushort Bs[128][40];

    if (tid < 64) {
        int t  = t0 + tid;
        int tt = dir ? ((t < L) ? (L - 1 - t) : t) : t;
        toks[tid] = (r < B_) ? s1[r * T_ + tt] : s2[(r - B_) * T_ + tt];
    }
    __syncthreads();

    const ushort* Wih  = dir ? WihBb : WihBf;
    const float*  bias = dir ? b_b : b_f;

    f32x4 acc[2][4] = {};

    for (int k0 = 0; k0 < EP; k0 += 32) {
        {   // A: 64 rows x 32 k = 256 x uint4
            int row = tid >> 2, seg = tid & 3;
            *(uint4*)&As[row][seg * 8] =
                *(const uint4*)&embB[(long)toks[row] * EP + k0 + seg * 8];
        }
#pragma unroll
        for (int p = 0; p < 2; ++p) {   // B: 128 cols x 32 k = 512 x uint4
            int u = tid + p * 256;
            int row = u >> 2, seg = u & 3;
            *(uint4*)&Bs[row][seg * 8] =
                *(const uint4*)&Wih[(long)(N0 + row) * EP + k0 + seg * 8];
        }
        __syncthreads();
        bf16x8 af[2], bfr[4];
#pragma unroll
        for (int mt = 0; mt < 2; ++mt)
            af[mt] = *(const bf16x8*)&As[wm * 32 + mt * 16 + l15][q8];
#pragma unroll
        for (int nt = 0; nt < 4; ++nt)
            bfr[nt] = *(const bf16x8*)&Bs[wn * 64 + nt * 16 + l15][q8];
#pragma unroll
        for (int mt = 0; mt < 2; ++mt)
#pragma unroll
            for (int nt = 0; nt < 4; ++nt)
                acc[mt][nt] = MFMA(af[mt], bfr[nt], acc[mt][nt]);
        __syncthreads();
    }

    ushort* xout = dir ? xb : xf;
#pragma unroll
    for (int mt = 0; mt < 2; ++mt) {
        int m = r * T_ + t0 + wm * 32 + mt * 16 + (lane >> 4) * 4;
#pragma unroll
        for (int nt = 0; nt < 4; ++nt) {
            int col = N0 + wn * 64 + nt * 16 + l15;
            float bv = bias[col];
#pragma unroll
            for (int rg = 0; rg < 4; ++rg)
                xout[(long)(m + rg) * G4 + col] = f2bf(acc[mt][nt][rg] + bv);
        }
    }
}

// ---------------------------------------------------------------------------
// K2: one LSTM step, MFMA. Grid 128 = 2 streams x 4 rowblocks(32) x 16 jblocks(32).
// Wave g computes gate g's 32x32 pre-activation tile (K=512, sw-pipelined
// staging); gates exchanged via LDS; fused sigmoid/tanh c,h epilogue.
// h stored bf16 at [r][t+1][:], c fp32 in place.
// ---------------------------------------------------------------------------
__global__ __launch_bounds__(256) void k_step(
    int t,
    const ushort* __restrict__ xf, const ushort* __restrict__ xb,
    ushort* __restrict__ hfB, ushort* __restrict__ hbB,
    float* __restrict__ cF, float* __restrict__ cB,
    const ushort* __restrict__ WhhBf, const ushort* __restrict__ WhhBb)
{
    const int bx = blockIdx.x;
    const int s  = bx >> 6;          // stream: 0 fwd, 1 bwd
    const int rb = (bx >> 4) & 3;    // row block of 32
    const int jb = bx & 15;          // j block of 32
    const int r0 = rb * 32, j0 = jb * 32;

    const ushort* xW  = s ? xb : xf;
    const ushort* Whh = s ? WhhBb : WhhBf;
    ushort* hB  = s ? hbB : hfB;
    float*  cWs = s ? cB : cF;

    const int tid = threadIdx.x;
    const int lane = tid & 63;
    const int g = tid >> 6;          // wave = gate (i,f,g,o)
    const int l15 = lane & 15, q8 = (lane >> 4) * 8;

    __shared__ __align__(16) ushort As[32][72];
    __shared__ __align__(16) ushort Bs[128][72];
    __shared__ float Gs[4][32][33];

    f32x4 acc[2][2] = {};

    const int arow = tid >> 3, aseg = tid & 7;
    uint4 rA, rB[4];
    // prefetch k0 = 0
    rA = *(const uint4*)&hB[((long)(r0 + arow) * TS + t) * H_ + aseg * 8];
#pragma unroll
    for (int p = 0; p < 4; ++p) {
        int u = tid + p * 256;
        int ci = u >> 3, seg = u & 7;
        rB[p] = *(const uint4*)&Whh[(long)((ci >> 5) * H_ + j0 + (ci & 31)) * H_ + seg * 8];
    }

    for (int k0 = 0; k0 < H_; k0 += 64) {
        *(uint4*)&As[arow][aseg * 8] = rA;
#pragma unroll
        for (int p = 0; p < 4; ++p) {
            int u = tid + p * 256;
            int ci = u >> 3, seg = u & 7;
            *(uint4*)&Bs[ci][seg * 8] = rB[p];
        }
        __syncthreads();
        if (k0 + 64 < H_) {   // prefetch next K-slice while MFMAs run
            int kn = k0 + 64;
            rA = *(const uint4*)&hB[((long)(r0 + arow) * TS + t) * H_ + kn + aseg * 8];
#pragma unroll
            for (int p = 0; p < 4; ++p) {
                int u = tid + p * 256;
                int ci = u >> 3, seg = u & 7;
                rB[p] = *(const uint4*)&Whh[(long)((ci >> 5) * H_ + j0 + (ci & 31)) * H_ + kn + seg * 8];
            }
        }
#pragma unroll
        for (int ks = 0; ks < 2; ++ks) {
            bf16x8 a0 = *(const bf16x8*)&As[l15][ks * 32 + q8];
            bf16x8 a1 = *(const bf16x8*)&As[16 + l15][ks * 32 + q8];
            bf16x8 b0 = *(const bf16x8*)&Bs[g * 32 + l15][ks * 32 + q8];
            bf16x8 b1 = *(const bf16x8*)&Bs[g * 32 + 16 + l15][ks * 32 + q8];
            acc[0][0] = MFMA(a0, b0, acc[0][0]);
            acc[0][1] = MFMA(a0, b1, acc[0][1]);
            acc[1][0] = MFMA(a1, b0, acc[1][0]);
            acc[1][1] = MFMA(a1, b1, acc[1][1]);
        }
        __syncthreads();
    }

    // publish gate pre-activations to LDS
#pragma unroll
    for (int mt = 0; mt < 2; ++mt)
#pragma unroll
        for (int nt = 0; nt < 2; ++nt)
#pragma unroll
            for (int rg = 0; rg < 4; ++rg)
                Gs[g][mt * 16 + (lane >> 4) * 4 + rg][nt * 16 + l15] = acc[mt][nt][rg];
    __syncthreads();

    // cell update: 32x32 cells, 4 per thread
#pragma unroll
    for (int p = 0; p < 4; ++p) {
        int cid = tid + p * 256;
        int rr = cid >> 5, jj = cid & 31;
        long xbase = ((long)(r0 + rr) * T_ + t) * G4 + j0 + jj;
        float gi = Gs[0][rr][jj] + bf2f(xW[xbase + 0 * H_]);
        float gf = Gs[1][rr][jj] + bf2f(xW[xbase + 1 * H_]);
        float gg = Gs[2][rr][jj] + bf2f(xW[xbase + 2 * H_]);
        float go = Gs[3][rr][jj] + bf2f(xW[xbase + 3 * H_]);
        long cidx = (long)(r0 + rr) * H_ + j0 + jj;
        float cn = fsig(gf) * cWs[cidx] + fsig(gi) * ftanh(gg);
        float hn = fsig(go) * ftanh(cn);
        cWs[cidx] = cn;
        hB[((long)(r0 + rr) * TS + t + 1) * H_ + j0 + jj] = f2bf(hn);
    }
}

// ---------------------------------------------------------------------------
// K3a: U[m,c] = tanh(Hout[m,:] @ S1W^T) via bf16 MFMA. Tile 64(m) x 64(n),
// K = 1024 (concat hf | hb-unreversed). Dead t-half tiles skipped.
// ---------------------------------------------------------------------------
__global__ __launch_bounds__(256) void k_attn_mfma(
    const ushort* __restrict__ hfB, const ushort* __restrict__ hbB,
    const int* __restrict__ l1, const int* __restrict__ l2,
    const ushort* __restrict__ S1WB, float* __restrict__ U)
{
    const int r  = blockIdx.y >> 1;
    const int t0 = (blockIdx.y & 1) * 64;
    const int N0 = blockIdx.x * 64;
    const int L  = (r < B_) ? l1[r] : l2[r - B_];
    if (L <= t0) return;

    const int tid = threadIdx.x;
    const int lane = tid & 63, w = tid >> 6;
    const int wm = w & 1, wn = w >> 1;
    const int l15 = lane & 15, q8 = (lane >> 4) * 8;

    __shared__ __align__(16) ushort As[64][72];
    __shared__ __align__(16) ushort Bs[64][72];

    f32x4 acc[2][2] = {};

    for (int k0 = 0; k0 < 2 * H_; k0 += 64) {
#pragma unroll
        for (int p = 0; p < 2; ++p) {   // A: 64 rows x 64 k
            int u = tid + p * 256;
            int row = u >> 3, seg = u & 7;
            int tpos = t0 + row;
            int k = k0 + seg * 8;
            long idx;
            const ushort* src;
            if (k0 < H_) {
                src = hfB; idx = ((long)r * TS + tpos + 1) * H_ + k;
            } else {
                int tt = (tpos < L) ? (L - 1 - tpos) : tpos;
                src = hbB; idx = ((long)r * TS + tt + 1) * H_ + (k - H_);
            }
            *(uint4*)&As[row][seg * 8] = *(const uint4*)&src[idx];
        }
#pragma unroll
        for (int p = 0; p < 2; ++p) {   // B: 64 cols x 64 k
            int u = tid + p * 256;
            int row = u >> 3, seg = u & 7;
            *(uint4*)&Bs[row][seg * 8] =
                *(const uint4*)&S1WB[(long)(N0 + row) * (2 * H_) + k0 + seg * 8];
        }
        __syncthreads();
#pragma unroll
        for (int ks = 0; ks < 2; ++ks) {
            bf16x8 a0 = *(const bf16x8*)&As[wm * 32 + l15][ks * 32 + q8];
            bf16x8 a1 = *(const bf16x8*)&As[wm * 32 + 16 + l15][ks * 32 + q8];
            bf16x8 b0 = *(const bf16x8*)&Bs[wn * 32 + l15][ks * 32 + q8];
            bf16x8 b1 = *(const bf16x8*)&Bs[wn * 32 + 16 + l15][ks * 32 + q8];
            acc[0][0] = MFMA(a0, b0, acc[0][0]);
            acc[0][1] = MFMA(a0, b1, acc[0][1]);
            acc[1][0] = MFMA(a1, b0, acc[1][0]);
            acc[1][1] = MFMA(a1, b1, acc[1][1]);
        }
        __syncthreads();
    }
#pragma unroll
    for (int mt = 0; mt < 2; ++mt) {
        int m = r * T_ + t0 + wm * 32 + mt * 16 + (lane >> 4) * 4;
#pragma unroll
        for (int nt = 0; nt < 2; ++nt) {
            int col = N0 + wn * 32 + nt * 16 + l15;
#pragma unroll
            for (int rg = 0; rg < 4; ++rg)
                U[(long)(m + rg) * C_ + col] = ftanh(acc[mt][nt][rg]);
        }
    }
}

// ---------------------------------------------------------------------------
// K3b: per row r: scores = U@S2W (wave-parallel, coalesced), masked softmax,
// pooled = attn @ Hout (bf16 h reads).
// ---------------------------------------------------------------------------
__global__ __launch_bounds__(256) void k_attn_pool(
    const ushort* __restrict__ hfB, const ushort* __restrict__ hbB,
    const float* __restrict__ U, const float* __restrict__ S2W,
    const int* __restrict__ l1, const int* __restrict__ l2,
    float* __restrict__ pooled)
{
    const int r = blockIdx.x;
    const int L = (r < B_) ? l1[r] : l2[r - B_];
    const int tid = threadIdx.x;
    const int lane = tid & 63, w = tid >> 6;

    __shared__ float att[T_];

    for (int tt = w; tt < T_; tt += 4) {
        float p = 0.0f;
        if (tt < L) {
            const float* u = &U[(long)(r * T_ + tt) * C_];
            p = u[lane] * S2W[lane] + u[lane + 64] * S2W[lane + 64]
              + u[lane + 128] * S2W[lane + 128] + u[lane + 192] * S2W[lane + 192];
            for (int off = 32; off; off >>= 1) p += __shfl_down(p, off);
        }
        if (lane == 0) att[tt] = p;
    }
    __syncthreads();

    float mx = -1e30f;
    for (int tt = 0; tt < L; ++tt) mx = fmaxf(mx, att[tt]);
    __syncthreads();
    if (tid < T_) att[tid] = (tid < L) ? __expf(att[tid] - mx) : 0.0f;
    __syncthreads();
    float sum = 0.0f;
    for (int tt = 0; tt < L; ++tt) sum += att[tt];
    float inv = 1.0f / sum;

    for (int d = tid; d < 2 * H_; d += 256) {
        float a = 0.0f;
        for (int tt = 0; tt < L; ++tt) {
            float hv = (d < H_)
                ? bf2f(hfB[((long)r * TS + tt + 1) * H_ + d])
                : bf2f(hbB[((long)r * TS + (L - tt)) * H_ + (d - H_)]);
            a += att[tt] * hv;
        }
        pooled[(long)r * (2 * H_) + d] = a * inv;
    }
}

// ---------------------------------------------------------------------------
// K4: merged = [r1+r2, (r1-r2)^2]; out = sigmoid((merged@mlpW^T+mlpb)@outW^T+outb)
// ---------------------------------------------------------------------------
__global__ __launch_bounds__(256) void k_mlp_out(
    const float* __restrict__ pooled,
    const float* __restrict__ mlpW, const float* __restrict__ mlpb,
    const float* __restrict__ outW, const float* __restrict__ outb,
    float* __restrict__ out)
{
    const int b = blockIdx.x;
    const int tid = threadIdx.x;
    __shared__ float sm[2048];
    __shared__ float om[M_];
    __shared__ float red[256];

    for (int d = tid; d < 2048; d += 256) {
        float v;
        if (d < 1024) {
            v = pooled[(long)b * 1024 + d] + pooled[(long)(B_ + b) * 1024 + d];
        } else {
            int dd = d - 1024;
            float w = pooled[(long)b * 1024 + dd] - pooled[(long)(B_ + b) * 1024 + dd];
            v = w * w;
        }
        sm[d] = v;
    }
    __syncthreads();

    for (int mm = tid; mm < M_; mm += 256) {
        float a = mlpb[mm];
        const float* wrow = &mlpW[(long)mm * 2048];
        for (int k = 0; k < 2048; ++k) a += sm[k] * wrow[k];
        om[mm] = a;
    }
    __syncthreads();

    float p = om[tid] * outW[tid] + om[tid + 256] * outW[tid + 256];
    red[tid] = p;
    __syncthreads();
    for (int off = 128; off > 0; off >>= 1) {
        if (tid < off) red[tid] += red[tid + off];
        __syncthreads();
    }
    if (tid == 0) out[b] = 1.0f / (1.0f + __expf(-(red[0] + outb[0])));
}

// ---------------------------------------------------------------------------
extern "C" void kernel_launch(void* const* d_in, const int* in_sizes, int n_in,
                              void* d_out, int out_size, void* d_ws, size_t ws_size,
                              hipStream_t stream)
{
    const int*   s1    = (const int*)d_in[0];
    const int*   s2    = (const int*)d_in[1];
    const int*   l1    = (const int*)d_in[2];
    const int*   l2    = (const int*)d_in[3];
    const float* s1_h0 = (const float*)d_in[4];
    const float* s1_c0 = (const float*)d_in[5];
    const float* s2_h0 = (const float*)d_in[6];
    const float* s2_c0 = (const float*)d_in[7];
    const float* emb   = (const float*)d_in[8];
    const float* Wih_f = (const float*)d_in[9];
    const float* Whh_f = (const float*)d_in[10];
    const float* b_f   = (const float*)d_in[11];
    const float* Wih_b = (const float*)d_in[12];
    const float* Whh_b = (const float*)d_in[13];
    const float* b_b   = (const float*)d_in[14];
    const float* S1W   = (const float*)d_in[15];
    const float* S2W   = (const float*)d_in[16];
    const float* mlpW  = (const float*)d_in[17];
    const float* mlpb  = (const float*)d_in[18];
    const float* outW  = (const float*)d_in[19];
    const float* outb  = (const float*)d_in[20];
    float* out = (float*)d_out;

    // Workspace carve (~214 MB, all 16B-aligned)
    ushort* p16 = (ushort*)d_ws;
    ushort* embB  = p16;  p16 += (long)32000 * EP;
    ushort* WihBf = p16;  p16 += (long)G4 * EP;
    ushort* WihBb = p16;  p16 += (long)G4 * EP;
    ushort* WhhBf = p16;  p16 += (long)G4 * H_;
    ushort* WhhBb = p16;  p16 += (long)G4 * H_;
    ushort* S1WB  = p16;  p16 += (long)C_ * 2 * H_;
    ushort* xf    = p16;  p16 += (long)R_ * T_ * G4;
    ushort* xb    = p16;  p16 += (long)R_ * T_ * G4;
    ushort* hfB   = p16;  p16 += (long)R_ * TS * H_;
    ushort* hbB   = p16;  p16 += (long)R_ * TS * H_;
    float* pf = (float*)p16;
    float* cF     = pf;   pf += (long)R_ * H_;
    float* cB     = pf;   pf += (long)R_ * H_;
    float* U      = pf;   pf += (long)R_ * T_ * C_;
    float* pooled = pf;   pf += (long)R_ * 2 * H_;

    // P0/P1: weight conversion + state init
    k_cvt<<<32000, 256, 0, stream>>>(emb,   embB,  E_, EP);
    k_cvt<<<G4,    256, 0, stream>>>(Wih_f, WihBf, E_, EP);
    k_cvt<<<G4,    256, 0, stream>>>(Wih_b, WihBb, E_, EP);
    k_cvt<<<G4,    256, 0, stream>>>(Whh_f, WhhBf, H_, H_);
    k_cvt<<<G4,    256, 0, stream>>>(Whh_b, WhhBb, H_, H_);
    k_cvt<<<C_,    256, 0, stream>>>(S1W,   S1WB,  2 * H_, 2 * H_);
    k_init<<<R_, 256, 0, stream>>>(s1_h0, s1_c0, s2_h0, s2_c0, hfB, hbB, cF, cB);

    // K1: input GEMM
    k_embed_mfma<<<dim3(16, 256, 2), 256, 0, stream>>>(
        s1, s2, l1, l2, embB, WihBf, WihBb, b_f, b_b, xf, xb);

    // K2: recurrence
    for (int t = 0; t < T_; ++t)
        k_step<<<128, 256, 0, stream>>>(t, xf, xb, hfB, hbB, cF, cB, WhhBf, WhhBb);

    // K3: attention pooling
    k_attn_mfma<<<dim3(4, 256), 256, 0, stream>>>(hfB, hbB, l1, l2, S1WB, U);
    k_attn_pool<<<R_, 256, 0, stream>>>(hfB, hbB, U, S2W, l1, l2, pooled);

    // K4: MLP head
    k_mlp_out<<<B_, 256, 0, stream>>>(pooled, mlpW, mlpb, outW, outb, out);
}

// Round 3
// 1341.215 us; speedup vs baseline: 3.1231x; 1.6484x over previous
//
#include <hip/hip_runtime.h>
#include <hip/hip_bf16.h>

// Problem constants (fixed by the reference)
#define B_  64
#define T_  128
#define E_  300
#define EP  320     // E padded to multiple of 32 for MFMA K-loop
#define H_  512
#define G4  2048    // 4*H
#define R_  128     // 2*B (s1+s2 batched; shared LSTM weights)
#define C_  256
#define M_  512
#define TS  (T_ + 1)  // h time slots: slot 0 = h0, slot t+1 = h(t)

typedef short bf16x8 __attribute__((ext_vector_type(8)));
typedef float f32x4  __attribute__((ext_vector_type(4)));
#define MFMA(a, b, c) __builtin_amdgcn_mfma_f32_16x16x32_bf16((a), (b), (c), 0, 0, 0)

__device__ __forceinline__ float fsig(float x) { return 1.0f / (1.0f + __expf(-x)); }
__device__ __forceinline__ float ftanh(float x) {
    float a = fminf(fabsf(x), 15.0f);
    float e = __expf(2.0f * a);
    return copysignf((e - 1.0f) / (e + 1.0f), x);
}
__device__ __forceinline__ ushort f2bf(float f) {
    __hip_bfloat16 h = __float2bfloat16(f);
    return *reinterpret_cast<ushort*>(&h);
}
__device__ __forceinline__ float bf2f(ushort u) {
    __hip_bfloat16 h = *reinterpret_cast<__hip_bfloat16*>(&u);
    return __bfloat162float(h);
}

// ---------------------------------------------------------------------------
// P0: f32 -> bf16 row-wise convert with K padding (zeros in [sk, dk)).
// ---------------------------------------------------------------------------
__global__ __launch_bounds__(256) void k_cvt(const float* __restrict__ src,
                                             ushort* __restrict__ dst,
                                             int sk, int dk)
{
    const int r = blockIdx.x;
    for (int c = threadIdx.x; c < dk; c += 256)
        dst[(long)r * dk + c] = (c < sk) ? f2bf(src[(long)r * sk + c]) : (ushort)0;
}

// P1: init h slot 0 (bf16) and c (f32) from the h0/c0 inputs.
__global__ __launch_bounds__(256) void k_init(
    const float* __restrict__ s1_h0, const float* __restrict__ s1_c0,
    const float* __restrict__ s2_h0, const float* __restrict__ s2_c0,
    ushort* __restrict__ hfB, ushort* __restrict__ hbB,
    float* __restrict__ cF, float* __restrict__ cB)
{
    const int r = blockIdx.x;                    // 0..127
    const int rl = (r < B_) ? r : r - B_;
    const float* h0 = (r < B_) ? s1_h0 : s2_h0;  // [2][B][H]
    const float* c0 = (r < B_) ? s1_c0 : s2_c0;
    for (int j = threadIdx.x; j < H_; j += 256) {
        hfB[(long)r * TS * H_ + j] = f2bf(h0[(long)0 * B_ * H_ + (long)rl * H_ + j]);
        hbB[(long)r * TS * H_ + j] = f2bf(h0[(long)1 * B_ * H_ + (long)rl * H_ + j]);
        cF[r * H_ + j] = c0[(long)0 * B_ * H_ + (long)rl * H_ + j];
        cB[r * H_ + j] = c0[(long)1 * B_ * H_ + (long)rl * H_ + j];
    }
}

// ---------------------------------------------------------------------------
// K1: embedding gather + input GEMM via bf16 MFMA (unchanged from round 2).
// ---------------------------------------------------------------------------
__global__ __launch_bounds__(256) void k_embed_mfma(
    const int* __restrict__ s1, const int* __restrict__ s2,
    const int* __restrict__ l1, const int* __restrict__ l2,
    const ushort* __restrict__ embB,
    const ushort* __restrict__ WihBf, const ushort* __restrict__ WihBb,
    const float* __restrict__ b_f, const float* __restrict__ b_b,
    ushort* __restrict__ xf, ushort* __restrict__ xb)
{
    const int dir = blockIdx.z;
    const int r   = blockIdx.y >> 1;
    const int t0  = (blockIdx.y & 1) * 64;
    const int N0  = blockIdx.x * 128;
    const int L   = (r < B_) ? l1[r] : l2[r - B_];
    if (L <= t0) return;

    const int tid = threadIdx.x;
    const int lane = tid & 63, w = tid >> 6;
    const int wm = w & 1, wn = w >> 1;
    const int l15 = lane & 15, q8 = (lane >> 4) * 8;

    __shared__ int toks[64];
    __shared__ __align__(16) ushort As[64][40];
    __shared__ __align__(16) ushort Bs[128][40];

    if (tid < 64) {
        int t  = t0 + tid;
        int tt = dir ? ((t < L) ? (L - 1 - t) : t) : t;
        toks[tid] = (r < B_) ? s1[r * T_ + tt] : s2[(r - B_) * T_ + tt];
    }
    __syncthreads();

    const ushort* Wih  = dir ? WihBb : WihBf;
    const float*  bias = dir ? b_b : b_f;

    f32x4 acc[2][4] = {};

    for (int k0 = 0; k0 < EP; k0 += 32) {
        {   // A: 64 rows x 32 k
            int row = tid >> 2, seg = tid & 3;
            *(uint4*)&As[row][seg * 8] =
                *(const uint4*)&embB[(long)toks[row] * EP + k0 + seg * 8];
        }
#pragma unroll
        for (int p = 0; p < 2; ++p) {   // B: 128 cols x 32 k
            int u = tid + p * 256;
            int row = u >> 2, seg = u & 3;
            *(uint4*)&Bs[row][seg * 8] =
                *(const uint4*)&Wih[(long)(N0 + row) * EP + k0 + seg * 8];
        }
        __syncthreads();
        bf16x8 af[2], bfr[4];
#pragma unroll
        for (int mt = 0; mt < 2; ++mt)
            af[mt] = *(const bf16x8*)&As[wm * 32 + mt * 16 + l15][q8];
#pragma unroll
        for (int nt = 0; nt < 4; ++nt)
            bfr[nt] = *(const bf16x8*)&Bs[wn * 64 + nt * 16 + l15][q8];
#pragma unroll
        for (int mt = 0; mt < 2; ++mt)
#pragma unroll
            for (int nt = 0; nt < 4; ++nt)
                acc[mt][nt] = MFMA(af[mt], bfr[nt], acc[mt][nt]);
        __syncthreads();
    }

    ushort* xout = dir ? xb : xf;
#pragma unroll
    for (int mt = 0; mt < 2; ++mt) {
        int m = r * T_ + t0 + wm * 32 + mt * 16 + (lane >> 4) * 4;
#pragma unroll
        for (int nt = 0; nt < 4; ++nt) {
            int col = N0 + wn * 64 + nt * 16 + l15;
            float bv = bias[col];
#pragma unroll
            for (int rg = 0; rg < 4; ++rg)
                xout[(long)(m + rg) * G4 + col] = f2bf(acc[mt][nt][rg] + bv);
        }
    }
}

// ---------------------------------------------------------------------------
// K2 v2: one LSTM step. Grid 256 = 2 streams x 4 rowblocks(32) x 32 jblocks(16)
// -> all CUs busy. Double-buffered LDS: ONE barrier per K-slice; global
// prefetch of slice i+2 issued right after the barrier so its latency hides
// under a full slice of MFMAs. Wave g computes gate g's 32x16 tile.
// ---------------------------------------------------------------------------
__global__ __launch_bounds__(256) void k_step(
    int t,
    const ushort* __restrict__ xf, const ushort* __restrict__ xb,
    ushort* __restrict__ hfB, ushort* __restrict__ hbB,
    float* __restrict__ cF, float* __restrict__ cB,
    const ushort* __restrict__ WhhBf, const ushort* __restrict__ WhhBb)
{
    const int bx = blockIdx.x;
    const int s  = bx >> 7;          // stream: 0 fwd, 1 bwd
    const int rb = (bx >> 5) & 3;    // row block of 32
    const int jb = bx & 31;          // j block of 16
    const int r0 = rb * 32, j0 = jb * 16;

    const ushort* xW  = s ? xb : xf;
    const ushort* Whh = s ? WhhBb : WhhBf;
    ushort* hB  = s ? hbB : hfB;
    float*  cWs = s ? cB : cF;

    const int tid = threadIdx.x;
    const int lane = tid & 63;
    const int g = tid >> 6;          // wave = gate (i,f,g,o)
    const int l15 = lane & 15, q8 = (lane >> 4) * 8;

    __shared__ __align__(16) ushort As[2][32][72];   // 32 rows x 64 k
    __shared__ __align__(16) ushort Bs[2][64][72];   // 64 cols (gate*16+jj) x 64 k
    __shared__ float Gs[4][32][17];                  // gate pre-acts 32 x 16

    f32x4 acc0 = {}, acc1 = {};

    // staging indices
    const int arow = tid >> 3, aseg = tid & 7;       // A: 256 x uint4
    const long abase = ((long)(r0 + arow) * TS + t) * H_ + aseg * 8;
    // B: 512 x uint4 (2 per thread)
    int ci0 = tid >> 3,       sg0 = tid & 7;
    int ci1 = (tid + 256) >> 3, sg1 = tid & 7;       // (tid+256)&7 == tid&7
    const long bbase0 = ((long)((ci0 >> 4) * H_ + j0 + (ci0 & 15))) * H_ + sg0 * 8;
    const long bbase1 = ((long)((ci1 >> 4) * H_ + j0 + (ci1 & 15))) * H_ + sg1 * 8;

    uint4 rA, rB0, rB1;

    // slice 0 -> buf 0
    rA  = *(const uint4*)&hB[abase];
    rB0 = *(const uint4*)&Whh[bbase0];
    rB1 = *(const uint4*)&Whh[bbase1];
    *(uint4*)&As[0][arow][aseg * 8] = rA;
    *(uint4*)&Bs[0][ci0][sg0 * 8]   = rB0;
    *(uint4*)&Bs[0][ci1][sg1 * 8]   = rB1;
    __syncthreads();
    // prefetch slice 1
    rA  = *(const uint4*)&hB[abase + 64];
    rB0 = *(const uint4*)&Whh[bbase0 + 64];
    rB1 = *(const uint4*)&Whh[bbase1 + 64];

#pragma unroll
    for (int i = 0; i < 8; ++i) {
        const int cur = i & 1;
        // MFMAs on buf[cur]
#pragma unroll
        for (int ks = 0; ks < 2; ++ks) {
            bf16x8 a0 = *(const bf16x8*)&As[cur][l15][ks * 32 + q8];
            bf16x8 a1 = *(const bf16x8*)&As[cur][16 + l15][ks * 32 + q8];
            bf16x8 b0 = *(const bf16x8*)&Bs[cur][g * 16 + l15][ks * 32 + q8];
            acc0 = MFMA(a0, b0, acc0);
            acc1 = MFMA(a1, b0, acc1);
        }
        if (i + 1 < 8) {
            // store prefetched slice i+1 into the other buffer
            *(uint4*)&As[cur ^ 1][arow][aseg * 8] = rA;
            *(uint4*)&Bs[cur ^ 1][ci0][sg0 * 8]   = rB0;
            *(uint4*)&Bs[cur ^ 1][ci1][sg1 * 8]   = rB1;
            __syncthreads();
            if (i + 2 < 8) {   // prefetch slice i+2 (latency hidden by next slice's MFMAs)
                const int kn = (i + 2) * 64;
                rA  = *(const uint4*)&hB[abase + kn];
                rB0 = *(const uint4*)&Whh[bbase0 + kn];
                rB1 = *(const uint4*)&Whh[bbase1 + kn];
            }
        }
    }

    // publish gate pre-activations (C layout: col=lane&15, row=(lane>>4)*4+rg)
#pragma unroll
    for (int rg = 0; rg < 4; ++rg) {
        Gs[g][(lane >> 4) * 4 + rg][l15]      = acc0[rg];
        Gs[g][16 + (lane >> 4) * 4 + rg][l15] = acc1[rg];
    }
    __syncthreads();

    // cell update: 32 rows x 16 j = 512 cells, 2 per thread
#pragma unroll
    for (int p = 0; p < 2; ++p) {
        int cid = tid + p * 256;
        int rr = cid >> 4, jj = cid & 15;
        long xbase = ((long)(r0 + rr) * T_ + t) * G4 + j0 + jj;
        float gi = Gs[0][rr][jj] + bf2f(xW[xbase + 0 * H_]);
        float gf = Gs[1][rr][jj] + bf2f(xW[xbase + 1 * H_]);
        float gg = Gs[2][rr][jj] + bf2f(xW[xbase + 2 * H_]);
        float go = Gs[3][rr][jj] + bf2f(xW[xbase + 3 * H_]);
        long cidx = (long)(r0 + rr) * H_ + j0 + jj;
        float cn = fsig(gf) * cWs[cidx] + fsig(gi) * ftanh(gg);
        float hn = fsig(go) * ftanh(cn);
        cWs[cidx] = cn;
        hB[((long)(r0 + rr) * TS + t + 1) * H_ + j0 + jj] = f2bf(hn);
    }
}

// ---------------------------------------------------------------------------
// K3a: U[m,c] = tanh(Hout[m,:] @ S1W^T) via bf16 MFMA (unchanged).
// ---------------------------------------------------------------------------
__global__ __launch_bounds__(256) void k_attn_mfma(
    const ushort* __restrict__ hfB, const ushort* __restrict__ hbB,
    const int* __restrict__ l1, const int* __restrict__ l2,
    const ushort* __restrict__ S1WB, float* __restrict__ U)
{
    const int r  = blockIdx.y >> 1;
    const int t0 = (blockIdx.y & 1) * 64;
    const int N0 = blockIdx.x * 64;
    const int L  = (r < B_) ? l1[r] : l2[r - B_];
    if (L <= t0) return;

    const int tid = threadIdx.x;
    const int lane = tid & 63, w = tid >> 6;
    const int wm = w & 1, wn = w >> 1;
    const int l15 = lane & 15, q8 = (lane >> 4) * 8;

    __shared__ __align__(16) ushort As[64][72];
    __shared__ __align__(16) ushort Bs[64][72];

    f32x4 acc[2][2] = {};

    for (int k0 = 0; k0 < 2 * H_; k0 += 64) {
#pragma unroll
        for (int p = 0; p < 2; ++p) {   // A: 64 rows x 64 k
            int u = tid + p * 256;
            int row = u >> 3, seg = u & 7;
            int tpos = t0 + row;
            int k = k0 + seg * 8;
            long idx;
            const ushort* src;
            if (k0 < H_) {
                src = hfB; idx = ((long)r * TS + tpos + 1) * H_ + k;
            } else {
                int tt = (tpos < L) ? (L - 1 - tpos) : tpos;
                src = hbB; idx = ((long)r * TS + tt + 1) * H_ + (k - H_);
            }
            *(uint4*)&As[row][seg * 8] = *(const uint4*)&src[idx];
        }
#pragma unroll
        for (int p = 0; p < 2; ++p) {   // B: 64 cols x 64 k
            int u = tid + p * 256;
            int row = u >> 3, seg = u & 7;
            *(uint4*)&Bs[row][seg * 8] =
                *(const uint4*)&S1WB[(long)(N0 + row) * (2 * H_) + k0 + seg * 8];
        }
        __syncthreads();
#pragma unroll
        for (int ks = 0; ks < 2; ++ks) {
            bf16x8 a0 = *(const bf16x8*)&As[wm * 32 + l15][ks * 32 + q8];
            bf16x8 a1 = *(const bf16x8*)&As[wm * 32 + 16 + l15][ks * 32 + q8];
            bf16x8 b0 = *(const bf16x8*)&Bs[wn * 32 + l15][ks * 32 + q8];
            bf16x8 b1 = *(const bf16x8*)&Bs[wn * 32 + 16 + l15][ks * 32 + q8];
            acc[0][0] = MFMA(a0, b0, acc[0][0]);
            acc[0][1] = MFMA(a0, b1, acc[0][1]);
            acc[1][0] = MFMA(a1, b0, acc[1][0]);
            acc[1][1] = MFMA(a1, b1, acc[1][1]);
        }
        __syncthreads();
    }
#pragma unroll
    for (int mt = 0; mt < 2; ++mt) {
        int m = r * T_ + t0 + wm * 32 + mt * 16 + (lane >> 4) * 4;
#pragma unroll
        for (int nt = 0; nt < 2; ++nt) {
            int col = N0 + wn * 32 + nt * 16 + l15;
#pragma unroll
            for (int rg = 0; rg < 4; ++rg)
                U[(long)(m + rg) * C_ + col] = ftanh(acc[mt][nt][rg]);
        }
    }
}

// ---------------------------------------------------------------------------
// K3b: scores = U@S2W, masked softmax, pooled = attn @ Hout (unchanged).
// ---------------------------------------------------------------------------
__global__ __launch_bounds__(256) void k_attn_pool(
    const ushort* __restrict__ hfB, const ushort* __restrict__ hbB,
    const float* __restrict__ U, const float* __restrict__ S2W,
    const int* __restrict__ l1, const int* __restrict__ l2,
    float* __restrict__ pooled)
{
    const int r = blockIdx.x;
    const int L = (r < B_) ? l1[r] : l2[r - B_];
    const int tid = threadIdx.x;
    const int lane = tid & 63, w = tid >> 6;

    __shared__ float att[T_];

    for (int tt = w; tt < T_; tt += 4) {
        float p = 0.0f;
        if (tt < L) {
            const float* u = &U[(long)(r * T_ + tt) * C_];
            p = u[lane] * S2W[lane] + u[lane + 64] * S2W[lane + 64]
              + u[lane + 128] * S2W[lane + 128] + u[lane + 192] * S2W[lane + 192];
            for (int off = 32; off; off >>= 1) p += __shfl_down(p, off);
        }
        if (lane == 0) att[tt] = p;
    }
    __syncthreads();

    float mx = -1e30f;
    for (int tt = 0; tt < L; ++tt) mx = fmaxf(mx, att[tt]);
    __syncthreads();
    if (tid < T_) att[tid] = (tid < L) ? __expf(att[tid] - mx) : 0.0f;
    __syncthreads();
    float sum = 0.0f;
    for (int tt = 0; tt < L; ++tt) sum += att[tt];
    float inv = 1.0f / sum;

    for (int d = tid; d < 2 * H_; d += 256) {
        float a = 0.0f;
        for (int tt = 0; tt < L; ++tt) {
            float hv = (d < H_)
                ? bf2f(hfB[((long)r * TS + tt + 1) * H_ + d])
                : bf2f(hbB[((long)r * TS + (L - tt)) * H_ + (d - H_)]);
            a += att[tt] * hv;
        }
        pooled[(long)r * (2 * H_) + d] = a * inv;
    }
}

// ---------------------------------------------------------------------------
// K4a v2: om[b][mm] = merged[b] . mlpW[mm] + mlpb[mm]
// Grid (8 mm-groups of 64, 64 b). merged staged in LDS (8 KB); each wave
// computes 16 dots with coalesced float4 loads + shuffle reduce.
// ---------------------------------------------------------------------------
__global__ __launch_bounds__(256) void k_mlp1(
    const float* __restrict__ pooled,
    const float* __restrict__ mlpW, const float* __restrict__ mlpb,
    float* __restrict__ om)
{
    const int mg = blockIdx.x;      // 0..7
    const int b  = blockIdx.y;      // 0..63
    const int tid = threadIdx.x;
    const int lane = tid & 63, w = tid >> 6;

    __shared__ __align__(16) float sm[2048];

#pragma unroll
    for (int it = 0; it < 8; ++it) {
        int d = tid + it * 256;
        float v;
        if (d < 1024) {
            v = pooled[(long)b * 1024 + d] + pooled[(long)(B_ + b) * 1024 + d];
        } else {
            int dd = d - 1024;
            float x = pooled[(long)b * 1024 + dd] - pooled[(long)(B_ + b) * 1024 + dd];
            v = x * x;
        }
        sm[d] = v;
    }
    __syncthreads();

    for (int i = 0; i < 16; ++i) {
        int mm = mg * 64 + w * 16 + i;
        const float* wrow = &mlpW[(long)mm * 2048];
        float ax = 0.f, ay = 0.f, az = 0.f, aw = 0.f;
#pragma unroll
        for (int it = 0; it < 8; ++it) {
            int k = it * 256 + lane * 4;
            float4 wv = *(const float4*)&wrow[k];
            float4 sv = *(const float4*)&sm[k];
            ax += wv.x * sv.x; ay += wv.y * sv.y;
            az += wv.z * sv.z; aw += wv.w * sv.w;
        }
        float ssum = (ax + ay) + (az + aw);
        for (int off = 32; off; off >>= 1) ssum += __shfl_down(ssum, off);
        if (lane == 0) om[(long)b * M_ + mm] = ssum + mlpb[mm];
    }
}

// K4b: out[b] = sigmoid(om[b] . outW + outb)   (CLS = 1)
__global__ __launch_bounds__(256) void k_final(
    const float* __restrict__ om,
    const float* __restrict__ outW, const float* __restrict__ outb,
    float* __restrict__ out)
{
    const int b = blockIdx.x;
    const int tid = threadIdx.x;
    __shared__ float red[256];
    float p = om[(long)b * M_ + tid] * outW[tid]
            + om[(long)b * M_ + 256 + tid] * outW[256 + tid];
    red[tid] = p;
    __syncthreads();
    for (int off = 128; off > 0; off >>= 1) {
        if (tid < off) red[tid] += red[tid + off];
        __syncthreads();
    }
    if (tid == 0) out[b] = 1.0f / (1.0f + __expf(-(red[0] + outb[0])));
}

// ---------------------------------------------------------------------------
extern "C" void kernel_launch(void* const* d_in, const int* in_sizes, int n_in,
                              void* d_out, int out_size, void* d_ws, size_t ws_size,
                              hipStream_t stream)
{
    const int*   s1    = (const int*)d_in[0];
    const int*   s2    = (const int*)d_in[1];
    const int*   l1    = (const int*)d_in[2];
    const int*   l2    = (const int*)d_in[3];
    const float* s1_h0 = (const float*)d_in[4];
    const float* s1_c0 = (const float*)d_in[5];
    const float* s2_h0 = (const float*)d_in[6];
    const float* s2_c0 = (const float*)d_in[7];
    const float* emb   = (const float*)d_in[8];
    const float* Wih_f = (const float*)d_in[9];
    const float* Whh_f = (const float*)d_in[10];
    const float* b_f   = (const float*)d_in[11];
    const float* Wih_b = (const float*)d_in[12];
    const float* Whh_b = (const float*)d_in[13];
    const float* b_b   = (const float*)d_in[14];
    const float* S1W   = (const float*)d_in[15];
    const float* S2W   = (const float*)d_in[16];
    const float* mlpW  = (const float*)d_in[17];
    const float* mlpb  = (const float*)d_in[18];
    const float* outW  = (const float*)d_in[19];
    const float* outb  = (const float*)d_in[20];
    float* out = (float*)d_out;

    // Workspace carve (~214 MB, all 16B-aligned)
    ushort* p16 = (ushort*)d_ws;
    ushort* embB  = p16;  p16 += (long)32000 * EP;
    ushort* WihBf = p16;  p16 += (long)G4 * EP;
    ushort* WihBb = p16;  p16 += (long)G4 * EP;
    ushort* WhhBf = p16;  p16 += (long)G4 * H_;
    ushort* WhhBb = p16;  p16 += (long)G4 * H_;
    ushort* S1WB  = p16;  p16 += (long)C_ * 2 * H_;
    ushort* xf    = p16;  p16 += (long)R_ * T_ * G4;
    ushort* xb    = p16;  p16 += (long)R_ * T_ * G4;
    ushort* hfB   = p16;  p16 += (long)R_ * TS * H_;
    ushort* hbB   = p16;  p16 += (long)R_ * TS * H_;
    float* pf = (float*)p16;
    float* cF     = pf;   pf += (long)R_ * H_;
    float* cB     = pf;   pf += (long)R_ * H_;
    float* U      = pf;   pf += (long)R_ * T_ * C_;
    float* pooled = pf;   pf += (long)R_ * 2 * H_;
    float* om     = pf;   pf += (long)B_ * M_;

    // P0/P1: weight conversion + state init
    k_cvt<<<32000, 256, 0, stream>>>(emb,   embB,  E_, EP);
    k_cvt<<<G4,    256, 0, stream>>>(Wih_f, WihBf, E_, EP);
    k_cvt<<<G4,    256, 0, stream>>>(Wih_b, WihBb, E_, EP);
    k_cvt<<<G4,    256, 0, stream>>>(Whh_f, WhhBf, H_, H_);
    k_cvt<<<G4,    256, 0, stream>>>(Whh_b, WhhBb, H_, H_);
    k_cvt<<<C_,    256, 0, stream>>>(S1W,   S1WB,  2 * H_, 2 * H_);
    k_init<<<R_, 256, 0, stream>>>(s1_h0, s1_c0, s2_h0, s2_c0, hfB, hbB, cF, cB);

    // K1: input GEMM
    k_embed_mfma<<<dim3(16, 256, 2), 256, 0, stream>>>(
        s1, s2, l1, l2, embB, WihBf, WihBb, b_f, b_b, xf, xb);

    // K2: recurrence (256 blocks/step, double-buffered)
    for (int t = 0; t < T_; ++t)
        k_step<<<256, 256, 0, stream>>>(t, xf, xb, hfB, hbB, cF, cB, WhhBf, WhhBb);

    // K3: attention pooling
    k_attn_mfma<<<dim3(4, 256), 256, 0, stream>>>(hfB, hbB, l1, l2, S1WB, U);
    k_attn_pool<<<R_, 256, 0, stream>>>(hfB, hbB, U, S2W, l1, l2, pooled);

    // K4: MLP head
    k_mlp1<<<dim3(8, B_), 256, 0, stream>>>(pooled, mlpW, mlpb, om);
    k_final<<<B_, 256, 0, stream>>>(om, outW, outb, out);
}